// Round 15
// baseline (1994.934 us; speedup 1.0000x reference)
//
#include <hip/hip_runtime.h>
#include <hip/hip_bf16.h>

// ---------------------------------------------------------------------------
// TernaryDense: C[M,N] = A[M,K] (fp32) @ ternary(W[K,N]) (fp32)
// Round 15: r14 (B-in-registers) with the vmcnt-queue order fixed:
// B fragment loads are issued BEFORE the A stage, so the compiler's wait
// before MFMA is vmcnt(16) (B only) and the A-stage pipeline is never
// drained mid-iteration (r14 drained it every iter -> 163us).
// Also launch_bounds(512,4): VGPR<=128 + 64KB LDS -> 2 blocks/CU resident.
// Everything else = r14: fragment-tiled B [N/16][K/64][64][16], A in LDS
// with r9's XOR-swizzle staging, one phase per K-tile, 64 MFMA i8 16x16x64.
// ---------------------------------------------------------------------------

#define LDSP(p) ((__attribute__((address_space(3))) void*)(p))
#define GLBP(p) ((const __attribute__((address_space(1))) void*)(p))

typedef __attribute__((ext_vector_type(4))) int i32x4;

static __device__ __forceinline__ signed char tern_i8(float v) {
    float a = fabsf(v);
    if (a >= 0.5f && a < 1.5f) return (v > 0.0f) ? (signed char)1 : (signed char)-1;
    return (signed char)0;
}

// --- pre-pass 1: per-row absmax + quantize A -> i8 (row-major), scales ------
__global__ __launch_bounds__(256) void quantA_kernel(
    const float* __restrict__ A, signed char* __restrict__ Aq,
    float* __restrict__ scales) {
    const int row = blockIdx.x;
    const int t = threadIdx.x;
    const int lane = t & 63;
    const int wave = t >> 6;
    const float* ar = A + (size_t)row * 4096;

    float4 v[4];
    float mx = 0.0f;
#pragma unroll
    for (int i = 0; i < 4; ++i) {
        v[i] = *(const float4*)(ar + t * 16 + i * 4);
        mx = fmaxf(mx, fmaxf(fmaxf(fabsf(v[i].x), fabsf(v[i].y)),
                             fmaxf(fabsf(v[i].z), fabsf(v[i].w))));
    }
#pragma unroll
    for (int off = 32; off; off >>= 1) mx = fmaxf(mx, __shfl_xor(mx, off));
    __shared__ float wmax[4];
    if (lane == 0) wmax[wave] = mx;
    __syncthreads();
    const float m = fmaxf(fmaxf(wmax[0], wmax[1]), fmaxf(wmax[2], wmax[3]));
    const float inv = (m > 0.0f) ? 127.0f / m : 0.0f;
    if (t == 0) scales[row] = (m > 0.0f) ? m / 127.0f : 0.0f;

    signed char q[16];
#pragma unroll
    for (int i = 0; i < 4; ++i) {
        const float* pv = (const float*)&v[i];
#pragma unroll
        for (int j = 0; j < 4; ++j) {
            float qf = rintf(pv[j] * inv);
            qf = fminf(127.0f, fmaxf(-127.0f, qf));
            q[i * 4 + j] = (signed char)(int)qf;
        }
    }
    *(int4*)(Aq + (size_t)row * 4096 + t * 16) = *(const int4*)q;
}

// --- pre-pass 2: ternarize W[K,N] -> i8, FRAGMENT-tiled transpose -----------
// Wt layout: [f = col/16][q = k/64][lane][16B]; lane l holds col f*16+(l&15),
// k = q*64 + (l>>4)*16 + e  (exactly the mfma_i32_16x16x64_i8 B fragment).
__global__ __launch_bounds__(256) void ternT_kernel(
    const float* __restrict__ W, signed char* __restrict__ Wt, int K, int N) {
    __shared__ signed char tile[64][68];
    const int k0 = blockIdx.y * 64;
    const int n0 = blockIdx.x * 64;
    const int t = threadIdx.x;
#pragma unroll
    for (int i = 0; i < 4; ++i) {
        int e = i * 1024 + t * 4;
        int r = e >> 6, c = e & 63;
        float4 v = *(const float4*)(W + (size_t)(k0 + r) * N + n0 + c);
        tile[r][c + 0] = tern_i8(v.x);
        tile[r][c + 1] = tern_i8(v.y);
        tile[r][c + 2] = tern_i8(v.z);
        tile[r][c + 3] = tern_i8(v.w);
    }
    __syncthreads();
    // 4 fragments per 64x64 tile (4 col-groups x 1 kchunk); 64 lanes x 16B
    const int fp = t >> 6;     // 0..3 col-group
    const int l = t & 63;
    signed char o[16];
#pragma unroll
    for (int e = 0; e < 16; ++e)
        o[e] = tile[(l >> 4) * 16 + e][fp * 16 + (l & 15)];
    const size_t f_g = (size_t)(n0 >> 4) + fp;
    const size_t q_g = (size_t)(k0 >> 6);
    *(int4*)(Wt + ((f_g * (K / 64) + q_g) * 64 + l) * 16) = *(const int4*)o;
}

// --- B-in-reg GEMM, i8 mfma 16x16x64, A LDS double-buffered -----------------
#define BM 256
#define BN 256
#define BKB 128   // K-tile depth (i8 elems); A rows are 128B

#define FENCE() asm volatile("" ::: "memory")
#define BAR()                          \
    do {                               \
        FENCE();                       \
        __builtin_amdgcn_s_barrier();  \
        FENCE();                       \
    } while (0)

template <int N, int K>
__global__ __launch_bounds__(512, 4) void gemmbr_kernel(
    const signed char* __restrict__ Aq,  // M x K i8 row-major
    const signed char* __restrict__ Bt,  // tiled [N/16][K/64][64][16]
    const float* __restrict__ scales,    // M
    float* __restrict__ C, int M) {
    __shared__ alignas(16) signed char ldsA[2][BM * BKB];  // 2 x 32 KB

    const int t = threadIdx.x;
    const int lane = t & 63;
    const int wave = t >> 6;
    const int wm = wave >> 2;   // 0..1 -> 128 rows
    const int wn = wave & 3;    // 0..3 -> 64 cols
    const int l15 = lane & 15;
    const int kgrp = lane >> 4; // 0..3

    // T1: bijective XCD swizzle (nwg % 8 == 0: 512)
    const int nbx = N / BN;
    const int nwg = nbx * (M / BM);
    const int qq = nwg >> 3;
    const int swz = ((int)blockIdx.x & 7) * qq + ((int)blockIdx.x >> 3);
    const int brow = (swz / nbx) * BM;
    const int bcol = (swz % nbx) * BN;

    constexpr int NKT = K / BKB;  // 32
    constexpr int QK = K / 64;    // 64 kchunks total

    // stage A K-tile kt into buffer b (32KB, 4 instr/thread).
    // LDS dest linear; inverse XOR swizzle on the GLOBAL source (r9 exact).
    auto stageA = [&](int b, int kt) {
#pragma unroll
        for (int iss = 0; iss < 4; ++iss) {
            int Lb = iss * 8192 + t * 16;            // byte in 32KB tile
            int row = Lb >> 7;                        // 0..255
            int kb = (Lb & 127) ^ ((row & 7) << 4);
            const signed char* src =
                Aq + (size_t)(brow + row) * K + (size_t)kt * BKB + kb;
            signed char* dst = &ldsA[b][0] + iss * 8192 + wave * 1024;
            __builtin_amdgcn_global_load_lds(GLBP(src), LDSP(dst), 16, 0, 0);
        }
    };

    auto read_A = [&](int b, int mf, int ks) -> i32x4 {
        int row = wm * 128 + mf * 16 + l15;
        int kb = (ks * 64 + kgrp * 16) ^ ((row & 7) << 4);
        return *(const i32x4*)(&ldsA[b][0] + row * 128 + kb);
    };
    // B fragment (nf, ks) of K-tile kt: one coalesced 1KB load
    auto load_B = [&](int nf, int ks, int kt) -> i32x4 {
        const size_t f_g = (size_t)(bcol >> 4) + wn * 4 + nf;
        const size_t q_g = (size_t)kt * 2 + ks;
        return *(const i32x4*)(Bt + ((f_g * QK + q_g) * 64 + lane) * 16);
    };

    i32x4 acc[8][4] = {};

    // prologue: stage A(0) into buf0
    stageA(0, 0);
    asm volatile("s_waitcnt vmcnt(0)" ::: "memory");
    BAR();

    for (int kt = 0; kt < NKT; ++kt) {
        const int b = kt & 1;
        // 1) B fragments -> regs FIRST: MFMA's wait becomes vmcnt(16),
        //    leaving the A stage (issued next) in flight across the MFMAs.
        i32x4 bf[4][2];
#pragma unroll
        for (int nf = 0; nf < 4; ++nf)
#pragma unroll
            for (int ks = 0; ks < 2; ++ks) bf[nf][ks] = load_B(nf, ks, kt);
        // 2) stage next A tile (retired by the END-of-iter vmcnt(0), ~2600cyc)
        stageA(b ^ 1, (kt + 1) & (NKT - 1));
        // 3) A fragments from LDS
        i32x4 af[8][2];
#pragma unroll
        for (int ks = 0; ks < 2; ++ks)
#pragma unroll
            for (int mf = 0; mf < 8; ++mf) af[mf][ks] = read_A(b, mf, ks);
        // 4) 64 MFMA, ks-outer (32 independent chains per ks)
        __builtin_amdgcn_s_setprio(1);
#pragma unroll
        for (int ks = 0; ks < 2; ++ks)
#pragma unroll
            for (int mf = 0; mf < 8; ++mf)
#pragma unroll
                for (int nf = 0; nf < 4; ++nf)
                    acc[mf][nf] = __builtin_amdgcn_mfma_i32_16x16x64_i8(
                        af[mf][ks], bf[nf][ks], acc[mf][nf], 0, 0, 0);
        __builtin_amdgcn_s_setprio(0);
        // 5) next buffer ready; all reads of buf b already in regs
        asm volatile("s_waitcnt vmcnt(0)" ::: "memory");
        BAR();
    }

    // epilogue: C/D col = lane&15, row = (lane>>4)*4 + reg; scale per row
    const int crow0 = brow + wm * 128;
    const int ccol0 = bcol + wn * 64;
#pragma unroll
    for (int mf = 0; mf < 8; ++mf)
#pragma unroll
        for (int r = 0; r < 4; ++r) {
            const int row = crow0 + mf * 16 + kgrp * 4 + r;
            const float sc = scales[row];
#pragma unroll
            for (int nf = 0; nf < 4; ++nf) {
                int col = ccol0 + nf * 16 + l15;
                C[(size_t)row * N + col] = (float)acc[mf][nf][r] * sc;
            }
        }
}

// --- fallback: naive fp32 (never expected to trigger) -----------------------
__global__ void naive_kernel(const float* __restrict__ A, const float* __restrict__ W,
                             float* __restrict__ C, int M, int N, int K) {
    int col = blockIdx.x * blockDim.x + threadIdx.x;
    int row = blockIdx.y;
    if (col >= N || row >= M) return;
    float s = 0.0f;
    for (int k = 0; k < K; ++k) {
        float w = W[(size_t)k * N + col];
        float a = fabsf(w);
        if (a >= 0.5f && a < 1.5f) s += (w > 0.0f) ? A[(size_t)row * K + k] : -A[(size_t)row * K + k];
    }
    C[(size_t)row * N + col] = s;
}

extern "C" void kernel_launch(void* const* d_in, const int* in_sizes, int n_in,
                              void* d_out, int out_size, void* d_ws, size_t ws_size,
                              hipStream_t stream) {
    const float* A = (const float*)d_in[0];  // [M,K]
    const float* W = (const float*)d_in[1];  // [K,N]
    float* C = (float*)d_out;

    constexpr int K = 4096, N = 4096;
    const int M = in_sizes[0] / K;  // 8192

    const size_t needAq = (size_t)M * K;
    const size_t needWt = (size_t)N * K;
    const size_t needSc = (size_t)M * 4;
    const bool ok = (M % BM == 0) && (ws_size >= needAq + needWt + needSc);
    if (!ok) {
        dim3 grid((N + 255) / 256, M);
        naive_kernel<<<grid, 256, 0, stream>>>(A, W, C, M, N, K);
        return;
    }

    signed char* Aq = (signed char*)d_ws;
    signed char* Wt = (signed char*)d_ws + needAq;
    float* scales = (float*)((char*)d_ws + needAq + needWt);

    quantA_kernel<<<dim3(M), 256, 0, stream>>>(A, Aq, scales);
    ternT_kernel<<<dim3(N / 64, K / 64), 256, 0, stream>>>(W, Wt, K, N);

    const int nwg = (M / BM) * (N / BN);  // 512
    gemmbr_kernel<N, K><<<dim3(nwg), 512, 0, stream>>>(Aq, Wt, scales, C, M);
}

// Round 16
// 194.174 us; speedup vs baseline: 10.2739x; 10.2739x over previous
//
#include <hip/hip_runtime.h>
#include <hip/hip_bf16.h>

// ---------------------------------------------------------------------------
// TernaryDense: C[M,N] = A[M,K] (fp32) @ ternary(W[K,N]) (fp32)
// Round 16: r15's load-order fix WITHOUT the (512,4) bound that spilled the
// accumulators to scratch (r15: VGPR capped 128 < ~180 live -> 9.8GB scratch
// traffic, 1990us). Back to launch_bounds(512,2) (r14's 124 VGPR, no spill).
// Only delta vs r14: B fragment loads issued BEFORE stageA, so the
// pre-MFMA wait retires only B (8 newest loads) and the A-stage DMA stays
// in flight across the MFMA burst; end-of-iter vmcnt(0) is ~2600cyc after
// the stage issue -> covered.
// ---------------------------------------------------------------------------

#define LDSP(p) ((__attribute__((address_space(3))) void*)(p))
#define GLBP(p) ((const __attribute__((address_space(1))) void*)(p))

typedef __attribute__((ext_vector_type(4))) int i32x4;

static __device__ __forceinline__ signed char tern_i8(float v) {
    float a = fabsf(v);
    if (a >= 0.5f && a < 1.5f) return (v > 0.0f) ? (signed char)1 : (signed char)-1;
    return (signed char)0;
}

// --- pre-pass 1: per-row absmax + quantize A -> i8 (row-major), scales ------
__global__ __launch_bounds__(256) void quantA_kernel(
    const float* __restrict__ A, signed char* __restrict__ Aq,
    float* __restrict__ scales) {
    const int row = blockIdx.x;
    const int t = threadIdx.x;
    const int lane = t & 63;
    const int wave = t >> 6;
    const float* ar = A + (size_t)row * 4096;

    float4 v[4];
    float mx = 0.0f;
#pragma unroll
    for (int i = 0; i < 4; ++i) {
        v[i] = *(const float4*)(ar + t * 16 + i * 4);
        mx = fmaxf(mx, fmaxf(fmaxf(fabsf(v[i].x), fabsf(v[i].y)),
                             fmaxf(fabsf(v[i].z), fabsf(v[i].w))));
    }
#pragma unroll
    for (int off = 32; off; off >>= 1) mx = fmaxf(mx, __shfl_xor(mx, off));
    __shared__ float wmax[4];
    if (lane == 0) wmax[wave] = mx;
    __syncthreads();
    const float m = fmaxf(fmaxf(wmax[0], wmax[1]), fmaxf(wmax[2], wmax[3]));
    const float inv = (m > 0.0f) ? 127.0f / m : 0.0f;
    if (t == 0) scales[row] = (m > 0.0f) ? m / 127.0f : 0.0f;

    signed char q[16];
#pragma unroll
    for (int i = 0; i < 4; ++i) {
        const float* pv = (const float*)&v[i];
#pragma unroll
        for (int j = 0; j < 4; ++j) {
            float qf = rintf(pv[j] * inv);
            qf = fminf(127.0f, fmaxf(-127.0f, qf));
            q[i * 4 + j] = (signed char)(int)qf;
        }
    }
    *(int4*)(Aq + (size_t)row * 4096 + t * 16) = *(const int4*)q;
}

// --- pre-pass 2: ternarize W[K,N] -> i8, FRAGMENT-tiled transpose -----------
// Wt layout: [f = col/16][q = k/64][lane][16B]; lane l holds col f*16+(l&15),
// k = q*64 + (l>>4)*16 + e  (exactly the mfma_i32_16x16x64_i8 B fragment).
__global__ __launch_bounds__(256) void ternT_kernel(
    const float* __restrict__ W, signed char* __restrict__ Wt, int K, int N) {
    __shared__ signed char tile[64][68];
    const int k0 = blockIdx.y * 64;
    const int n0 = blockIdx.x * 64;
    const int t = threadIdx.x;
#pragma unroll
    for (int i = 0; i < 4; ++i) {
        int e = i * 1024 + t * 4;
        int r = e >> 6, c = e & 63;
        float4 v = *(const float4*)(W + (size_t)(k0 + r) * N + n0 + c);
        tile[r][c + 0] = tern_i8(v.x);
        tile[r][c + 1] = tern_i8(v.y);
        tile[r][c + 2] = tern_i8(v.z);
        tile[r][c + 3] = tern_i8(v.w);
    }
    __syncthreads();
    // 4 fragments per 64x64 tile (4 col-groups x 1 kchunk); 64 lanes x 16B
    const int fp = t >> 6;     // 0..3 col-group
    const int l = t & 63;
    signed char o[16];
#pragma unroll
    for (int e = 0; e < 16; ++e)
        o[e] = tile[(l >> 4) * 16 + e][fp * 16 + (l & 15)];
    const size_t f_g = (size_t)(n0 >> 4) + fp;
    const size_t q_g = (size_t)(k0 >> 6);
    *(int4*)(Wt + ((f_g * (K / 64) + q_g) * 64 + l) * 16) = *(const int4*)o;
}

// --- B-in-reg GEMM, i8 mfma 16x16x64, A LDS double-buffered -----------------
#define BM 256
#define BN 256
#define BKB 128   // K-tile depth (i8 elems); A rows are 128B

#define FENCE() asm volatile("" ::: "memory")
#define BAR()                          \
    do {                               \
        FENCE();                       \
        __builtin_amdgcn_s_barrier();  \
        FENCE();                       \
    } while (0)

template <int N, int K>
__global__ __launch_bounds__(512, 2) void gemmbr_kernel(
    const signed char* __restrict__ Aq,  // M x K i8 row-major
    const signed char* __restrict__ Bt,  // tiled [N/16][K/64][64][16]
    const float* __restrict__ scales,    // M
    float* __restrict__ C, int M) {
    __shared__ alignas(16) signed char ldsA[2][BM * BKB];  // 2 x 32 KB

    const int t = threadIdx.x;
    const int lane = t & 63;
    const int wave = t >> 6;
    const int wm = wave >> 2;   // 0..1 -> 128 rows
    const int wn = wave & 3;    // 0..3 -> 64 cols
    const int l15 = lane & 15;
    const int kgrp = lane >> 4; // 0..3

    // T1: bijective XCD swizzle (nwg % 8 == 0: 512)
    const int nbx = N / BN;
    const int nwg = nbx * (M / BM);
    const int qq = nwg >> 3;
    const int swz = ((int)blockIdx.x & 7) * qq + ((int)blockIdx.x >> 3);
    const int brow = (swz / nbx) * BM;
    const int bcol = (swz % nbx) * BN;

    constexpr int NKT = K / BKB;  // 32
    constexpr int QK = K / 64;    // 64 kchunks total

    // stage A K-tile kt into buffer b (32KB, 4 instr/thread).
    // LDS dest linear; inverse XOR swizzle on the GLOBAL source (r9 exact).
    auto stageA = [&](int b, int kt) {
#pragma unroll
        for (int iss = 0; iss < 4; ++iss) {
            int Lb = iss * 8192 + t * 16;            // byte in 32KB tile
            int row = Lb >> 7;                        // 0..255
            int kb = (Lb & 127) ^ ((row & 7) << 4);
            const signed char* src =
                Aq + (size_t)(brow + row) * K + (size_t)kt * BKB + kb;
            signed char* dst = &ldsA[b][0] + iss * 8192 + wave * 1024;
            __builtin_amdgcn_global_load_lds(GLBP(src), LDSP(dst), 16, 0, 0);
        }
    };

    auto read_A = [&](int b, int mf, int ks) -> i32x4 {
        int row = wm * 128 + mf * 16 + l15;
        int kb = (ks * 64 + kgrp * 16) ^ ((row & 7) << 4);
        return *(const i32x4*)(&ldsA[b][0] + row * 128 + kb);
    };
    // B fragment (nf, ks) of K-tile kt: one coalesced 1KB load
    auto load_B = [&](int nf, int ks, int kt) -> i32x4 {
        const size_t f_g = (size_t)(bcol >> 4) + wn * 4 + nf;
        const size_t q_g = (size_t)kt * 2 + ks;
        return *(const i32x4*)(Bt + ((f_g * QK + q_g) * 64 + lane) * 16);
    };

    i32x4 acc[8][4] = {};

    // prologue: stage A(0) into buf0
    stageA(0, 0);
    asm volatile("s_waitcnt vmcnt(0)" ::: "memory");
    BAR();

    for (int kt = 0; kt < NKT; ++kt) {
        const int b = kt & 1;
        // 1) B fragments -> regs FIRST: pre-MFMA wait retires only B,
        //    the A stage (issued next) stays in flight across the MFMAs.
        i32x4 bf[4][2];
#pragma unroll
        for (int nf = 0; nf < 4; ++nf)
#pragma unroll
            for (int ks = 0; ks < 2; ++ks) bf[nf][ks] = load_B(nf, ks, kt);
        // 2) stage next A tile (retired by END-of-iter vmcnt(0), ~2600cyc)
        stageA(b ^ 1, (kt + 1) & (NKT - 1));
        // 3) A fragments from LDS
        i32x4 af[8][2];
#pragma unroll
        for (int ks = 0; ks < 2; ++ks)
#pragma unroll
            for (int mf = 0; mf < 8; ++mf) af[mf][ks] = read_A(b, mf, ks);
        // 4) 64 MFMA, ks-outer (32 independent chains per ks)
        __builtin_amdgcn_s_setprio(1);
#pragma unroll
        for (int ks = 0; ks < 2; ++ks)
#pragma unroll
            for (int mf = 0; mf < 8; ++mf)
#pragma unroll
                for (int nf = 0; nf < 4; ++nf)
                    acc[mf][nf] = __builtin_amdgcn_mfma_i32_16x16x64_i8(
                        af[mf][ks], bf[nf][ks], acc[mf][nf], 0, 0, 0);
        __builtin_amdgcn_s_setprio(0);
        // 5) next buffer ready; all reads of buf b already in regs
        asm volatile("s_waitcnt vmcnt(0)" ::: "memory");
        BAR();
    }

    // epilogue: C/D col = lane&15, row = (lane>>4)*4 + reg; scale per row
    const int crow0 = brow + wm * 128;
    const int ccol0 = bcol + wn * 64;
#pragma unroll
    for (int mf = 0; mf < 8; ++mf)
#pragma unroll
        for (int r = 0; r < 4; ++r) {
            const int row = crow0 + mf * 16 + kgrp * 4 + r;
            const float sc = scales[row];
#pragma unroll
            for (int nf = 0; nf < 4; ++nf) {
                int col = ccol0 + nf * 16 + l15;
                C[(size_t)row * N + col] = (float)acc[mf][nf][r] * sc;
            }
        }
}

// --- fallback: naive fp32 (never expected to trigger) -----------------------
__global__ void naive_kernel(const float* __restrict__ A, const float* __restrict__ W,
                             float* __restrict__ C, int M, int N, int K) {
    int col = blockIdx.x * blockDim.x + threadIdx.x;
    int row = blockIdx.y;
    if (col >= N || row >= M) return;
    float s = 0.0f;
    for (int k = 0; k < K; ++k) {
        float w = W[(size_t)k * N + col];
        float a = fabsf(w);
        if (a >= 0.5f && a < 1.5f) s += (w > 0.0f) ? A[(size_t)row * K + k] : -A[(size_t)row * K + k];
    }
    C[(size_t)row * N + col] = s;
}

extern "C" void kernel_launch(void* const* d_in, const int* in_sizes, int n_in,
                              void* d_out, int out_size, void* d_ws, size_t ws_size,
                              hipStream_t stream) {
    const float* A = (const float*)d_in[0];  // [M,K]
    const float* W = (const float*)d_in[1];  // [K,N]
    float* C = (float*)d_out;

    constexpr int K = 4096, N = 4096;
    const int M = in_sizes[0] / K;  // 8192

    const size_t needAq = (size_t)M * K;
    const size_t needWt = (size_t)N * K;
    const size_t needSc = (size_t)M * 4;
    const bool ok = (M % BM == 0) && (ws_size >= needAq + needWt + needSc);
    if (!ok) {
        dim3 grid((N + 255) / 256, M);
        naive_kernel<<<grid, 256, 0, stream>>>(A, W, C, M, N, K);
        return;
    }

    signed char* Aq = (signed char*)d_ws;
    signed char* Wt = (signed char*)d_ws + needAq;
    float* scales = (float*)((char*)d_ws + needAq + needWt);

    quantA_kernel<<<dim3(M), 256, 0, stream>>>(A, Aq, scales);
    ternT_kernel<<<dim3(N / 64, K / 64), 256, 0, stream>>>(W, Wt, K, N);

    const int nwg = (M / BM) * (N / BN);  // 512
    gemmbr_kernel<N, K><<<dim3(nwg), 512, 0, stream>>>(Aq, Wt, scales, C, M);
}

// Round 17
// 191.331 us; speedup vs baseline: 10.4266x; 1.0149x over previous
//
#include <hip/hip_runtime.h>
#include <hip/hip_bf16.h>

// ---------------------------------------------------------------------------
// TernaryDense: C[M,N] = A[M,K] (fp32) @ ternary(W[K,N]) (fp32)
// Round 17: r16 + sched_barrier(0) fences actually pinning the VMEM issue
// order {B loads} < {A stage} < {ds_reads/MFMA}. r14 and r16 benched
// IDENTICAL (163us) because nothing stopped the scheduler from mixing the
// stage into/before the B loads -> the pre-MFMA wait drained the stage DMA
// every iteration (~3500cyc/iter, matching the observed 36% MfmaUtil).
// With pinned order the pre-MFMA wait is vmcnt(16) (stage in flight) and
// the end-of-iter vmcnt(0) is ~2900cyc downstream of the stage -> covered.
// Two coarse fences/iter only (m141's per-instr pinning regressed; this is
// not that).
// ---------------------------------------------------------------------------

#define LDSP(p) ((__attribute__((address_space(3))) void*)(p))
#define GLBP(p) ((const __attribute__((address_space(1))) void*)(p))

typedef __attribute__((ext_vector_type(4))) int i32x4;

static __device__ __forceinline__ signed char tern_i8(float v) {
    float a = fabsf(v);
    if (a >= 0.5f && a < 1.5f) return (v > 0.0f) ? (signed char)1 : (signed char)-1;
    return (signed char)0;
}

// --- pre-pass 1: per-row absmax + quantize A -> i8 (row-major), scales ------
__global__ __launch_bounds__(256) void quantA_kernel(
    const float* __restrict__ A, signed char* __restrict__ Aq,
    float* __restrict__ scales) {
    const int row = blockIdx.x;
    const int t = threadIdx.x;
    const int lane = t & 63;
    const int wave = t >> 6;
    const float* ar = A + (size_t)row * 4096;

    float4 v[4];
    float mx = 0.0f;
#pragma unroll
    for (int i = 0; i < 4; ++i) {
        v[i] = *(const float4*)(ar + t * 16 + i * 4);
        mx = fmaxf(mx, fmaxf(fmaxf(fabsf(v[i].x), fabsf(v[i].y)),
                             fmaxf(fabsf(v[i].z), fabsf(v[i].w))));
    }
#pragma unroll
    for (int off = 32; off; off >>= 1) mx = fmaxf(mx, __shfl_xor(mx, off));
    __shared__ float wmax[4];
    if (lane == 0) wmax[wave] = mx;
    __syncthreads();
    const float m = fmaxf(fmaxf(wmax[0], wmax[1]), fmaxf(wmax[2], wmax[3]));
    const float inv = (m > 0.0f) ? 127.0f / m : 0.0f;
    if (t == 0) scales[row] = (m > 0.0f) ? m / 127.0f : 0.0f;

    signed char q[16];
#pragma unroll
    for (int i = 0; i < 4; ++i) {
        const float* pv = (const float*)&v[i];
#pragma unroll
        for (int j = 0; j < 4; ++j) {
            float qf = rintf(pv[j] * inv);
            qf = fminf(127.0f, fmaxf(-127.0f, qf));
            q[i * 4 + j] = (signed char)(int)qf;
        }
    }
    *(int4*)(Aq + (size_t)row * 4096 + t * 16) = *(const int4*)q;
}

// --- pre-pass 2: ternarize W[K,N] -> i8, FRAGMENT-tiled transpose -----------
// Wt layout: [f = col/16][q = k/64][lane][16B]; lane l holds col f*16+(l&15),
// k = q*64 + (l>>4)*16 + e  (exactly the mfma_i32_16x16x64_i8 B fragment).
__global__ __launch_bounds__(256) void ternT_kernel(
    const float* __restrict__ W, signed char* __restrict__ Wt, int K, int N) {
    __shared__ signed char tile[64][68];
    const int k0 = blockIdx.y * 64;
    const int n0 = blockIdx.x * 64;
    const int t = threadIdx.x;
#pragma unroll
    for (int i = 0; i < 4; ++i) {
        int e = i * 1024 + t * 4;
        int r = e >> 6, c = e & 63;
        float4 v = *(const float4*)(W + (size_t)(k0 + r) * N + n0 + c);
        tile[r][c + 0] = tern_i8(v.x);
        tile[r][c + 1] = tern_i8(v.y);
        tile[r][c + 2] = tern_i8(v.z);
        tile[r][c + 3] = tern_i8(v.w);
    }
    __syncthreads();
    // 4 fragments per 64x64 tile (4 col-groups x 1 kchunk); 64 lanes x 16B
    const int fp = t >> 6;     // 0..3 col-group
    const int l = t & 63;
    signed char o[16];
#pragma unroll
    for (int e = 0; e < 16; ++e)
        o[e] = tile[(l >> 4) * 16 + e][fp * 16 + (l & 15)];
    const size_t f_g = (size_t)(n0 >> 4) + fp;
    const size_t q_g = (size_t)(k0 >> 6);
    *(int4*)(Wt + ((f_g * (K / 64) + q_g) * 64 + l) * 16) = *(const int4*)o;
}

// --- B-in-reg GEMM, i8 mfma 16x16x64, A LDS double-buffered -----------------
#define BM 256
#define BN 256
#define BKB 128   // K-tile depth (i8 elems); A rows are 128B

#define FENCE() asm volatile("" ::: "memory")
#define BAR()                          \
    do {                               \
        FENCE();                       \
        __builtin_amdgcn_s_barrier();  \
        FENCE();                       \
    } while (0)

template <int N, int K>
__global__ __launch_bounds__(512, 2) void gemmbr_kernel(
    const signed char* __restrict__ Aq,  // M x K i8 row-major
    const signed char* __restrict__ Bt,  // tiled [N/16][K/64][64][16]
    const float* __restrict__ scales,    // M
    float* __restrict__ C, int M) {
    __shared__ alignas(16) signed char ldsA[2][BM * BKB];  // 2 x 32 KB

    const int t = threadIdx.x;
    const int lane = t & 63;
    const int wave = t >> 6;
    const int wm = wave >> 2;   // 0..1 -> 128 rows
    const int wn = wave & 3;    // 0..3 -> 64 cols
    const int l15 = lane & 15;
    const int kgrp = lane >> 4; // 0..3

    // T1: bijective XCD swizzle (nwg % 8 == 0: 512)
    const int nbx = N / BN;
    const int nwg = nbx * (M / BM);
    const int qq = nwg >> 3;
    const int swz = ((int)blockIdx.x & 7) * qq + ((int)blockIdx.x >> 3);
    const int brow = (swz / nbx) * BM;
    const int bcol = (swz % nbx) * BN;

    constexpr int NKT = K / BKB;  // 32
    constexpr int QK = K / 64;    // 64 kchunks total

    // stage A K-tile kt into buffer b (32KB, 4 instr/thread).
    // LDS dest linear; inverse XOR swizzle on the GLOBAL source (r9 exact).
    auto stageA = [&](int b, int kt) {
#pragma unroll
        for (int iss = 0; iss < 4; ++iss) {
            int Lb = iss * 8192 + t * 16;            // byte in 32KB tile
            int row = Lb >> 7;                        // 0..255
            int kb = (Lb & 127) ^ ((row & 7) << 4);
            const signed char* src =
                Aq + (size_t)(brow + row) * K + (size_t)kt * BKB + kb;
            signed char* dst = &ldsA[b][0] + iss * 8192 + wave * 1024;
            __builtin_amdgcn_global_load_lds(GLBP(src), LDSP(dst), 16, 0, 0);
        }
    };

    auto read_A = [&](int b, int mf, int ks) -> i32x4 {
        int row = wm * 128 + mf * 16 + l15;
        int kb = (ks * 64 + kgrp * 16) ^ ((row & 7) << 4);
        return *(const i32x4*)(&ldsA[b][0] + row * 128 + kb);
    };
    // B fragment (nf, ks) of K-tile kt: one coalesced 1KB load
    auto load_B = [&](int nf, int ks, int kt) -> i32x4 {
        const size_t f_g = (size_t)(bcol >> 4) + wn * 4 + nf;
        const size_t q_g = (size_t)kt * 2 + ks;
        return *(const i32x4*)(Bt + ((f_g * QK + q_g) * 64 + lane) * 16);
    };

    i32x4 acc[8][4] = {};

    // prologue: stage A(0) into buf0
    stageA(0, 0);
    asm volatile("s_waitcnt vmcnt(0)" ::: "memory");
    BAR();

    for (int kt = 0; kt < NKT; ++kt) {
        const int b = kt & 1;
        // 1) B fragments -> regs FIRST (oldest in vmcnt queue)
        i32x4 bf[4][2];
#pragma unroll
        for (int nf = 0; nf < 4; ++nf)
#pragma unroll
            for (int ks = 0; ks < 2; ++ks) bf[nf][ks] = load_B(nf, ks, kt);
        __builtin_amdgcn_sched_barrier(0);   // pin: B loads issued before stage
        // 2) stage next A tile (16 newest VMEM ops; retired by end-of-iter
        //    vmcnt(0), ~2900cyc downstream)
        stageA(b ^ 1, (kt + 1) & (NKT - 1));
        __builtin_amdgcn_sched_barrier(0);   // pin: stage before reads/MFMA
        // 3) A fragments from LDS
        i32x4 af[8][2];
#pragma unroll
        for (int ks = 0; ks < 2; ++ks)
#pragma unroll
            for (int mf = 0; mf < 8; ++mf) af[mf][ks] = read_A(b, mf, ks);
        // 4) 64 MFMA, ks-outer (32 independent chains per ks); the wait for
        //    bf here is vmcnt(16) -> stage stays in flight.
        __builtin_amdgcn_s_setprio(1);
#pragma unroll
        for (int ks = 0; ks < 2; ++ks)
#pragma unroll
            for (int mf = 0; mf < 8; ++mf)
#pragma unroll
                for (int nf = 0; nf < 4; ++nf)
                    acc[mf][nf] = __builtin_amdgcn_mfma_i32_16x16x64_i8(
                        af[mf][ks], bf[nf][ks], acc[mf][nf], 0, 0, 0);
        __builtin_amdgcn_s_setprio(0);
        // 5) next buffer ready; all reads of buf b already in regs
        asm volatile("s_waitcnt vmcnt(0)" ::: "memory");
        BAR();
    }

    // epilogue: C/D col = lane&15, row = (lane>>4)*4 + reg; scale per row
    const int crow0 = brow + wm * 128;
    const int ccol0 = bcol + wn * 64;
#pragma unroll
    for (int mf = 0; mf < 8; ++mf)
#pragma unroll
        for (int r = 0; r < 4; ++r) {
            const int row = crow0 + mf * 16 + kgrp * 4 + r;
            const float sc = scales[row];
#pragma unroll
            for (int nf = 0; nf < 4; ++nf) {
                int col = ccol0 + nf * 16 + l15;
                C[(size_t)row * N + col] = (float)acc[mf][nf][r] * sc;
            }
        }
}

// --- fallback: naive fp32 (never expected to trigger) -----------------------
__global__ void naive_kernel(const float* __restrict__ A, const float* __restrict__ W,
                             float* __restrict__ C, int M, int N, int K) {
    int col = blockIdx.x * blockDim.x + threadIdx.x;
    int row = blockIdx.y;
    if (col >= N || row >= M) return;
    float s = 0.0f;
    for (int k = 0; k < K; ++k) {
        float w = W[(size_t)k * N + col];
        float a = fabsf(w);
        if (a >= 0.5f && a < 1.5f) s += (w > 0.0f) ? A[(size_t)row * K + k] : -A[(size_t)row * K + k];
    }
    C[(size_t)row * N + col] = s;
}

extern "C" void kernel_launch(void* const* d_in, const int* in_sizes, int n_in,
                              void* d_out, int out_size, void* d_ws, size_t ws_size,
                              hipStream_t stream) {
    const float* A = (const float*)d_in[0];  // [M,K]
    const float* W = (const float*)d_in[1];  // [K,N]
    float* C = (float*)d_out;

    constexpr int K = 4096, N = 4096;
    const int M = in_sizes[0] / K;  // 8192

    const size_t needAq = (size_t)M * K;
    const size_t needWt = (size_t)N * K;
    const size_t needSc = (size_t)M * 4;
    const bool ok = (M % BM == 0) && (ws_size >= needAq + needWt + needSc);
    if (!ok) {
        dim3 grid((N + 255) / 256, M);
        naive_kernel<<<grid, 256, 0, stream>>>(A, W, C, M, N, K);
        return;
    }

    signed char* Aq = (signed char*)d_ws;
    signed char* Wt = (signed char*)d_ws + needAq;
    float* scales = (float*)((char*)d_ws + needAq + needWt);

    quantA_kernel<<<dim3(M), 256, 0, stream>>>(A, Aq, scales);
    ternT_kernel<<<dim3(N / 64, K / 64), 256, 0, stream>>>(W, Wt, K, N);

    const int nwg = (M / BM) * (N / BN);  // 512
    gemmbr_kernel<N, K><<<dim3(nwg), 512, 0, stream>>>(Aq, Wt, scales, C, M);
}